// Round 1
// baseline (1572.914 us; speedup 1.0000x reference)
//
#include <hip/hip_runtime.h>

#define K_IN  256
#define N_OUT 128
#define TILE_ROWS 64

// GEMM: h[M][128] = x[M][256] @ W[256][128] + b
// Block = 256 threads. Tile = 64 rows x 128 feats.
// Wave w (tid>>6) owns rows [w*16, w*16+16); lane f0 = tid&63 owns feats {f0, f0+64}.
// x tile staged in LDS (64KB); W streamed from global (128KB, L2-resident).
__global__ __launch_bounds__(256) void gcn_gemm(
    const float* __restrict__ x, const float* __restrict__ W,
    const float* __restrict__ bias, float* __restrict__ h, int M)
{
    __shared__ float xs[TILE_ROWS][K_IN];   // 64 KB
    const int tid  = threadIdx.x;
    const int row0 = blockIdx.x * TILE_ROWS;

    // stage x tile: 64 rows * 64 float4 each
    const int nvec = TILE_ROWS * (K_IN / 4);
    for (int i = tid; i < nvec; i += 256) {
        const int r = i >> 6;         // float4-index / 64
        const int c = i & 63;
        float4 v = make_float4(0.f, 0.f, 0.f, 0.f);
        const int row = row0 + r;
        if (row < M) v = reinterpret_cast<const float4*>(x + (size_t)row * K_IN)[c];
        reinterpret_cast<float4*>(&xs[r][0])[c] = v;
    }
    __syncthreads();

    const int f0    = tid & 63;
    const int rbase = (tid >> 6) * 16;

    float acc0[16], acc1[16];
#pragma unroll
    for (int i = 0; i < 16; ++i) { acc0[i] = 0.f; acc1[i] = 0.f; }

#pragma unroll 2
    for (int k4 = 0; k4 < K_IN / 4; ++k4) {
        float w0[4], w1[4];
#pragma unroll
        for (int j = 0; j < 4; ++j) {
            w0[j] = W[(size_t)(k4 * 4 + j) * N_OUT + f0];
            w1[j] = W[(size_t)(k4 * 4 + j) * N_OUT + f0 + 64];
        }
#pragma unroll
        for (int i = 0; i < 16; ++i) {
            const float4 xv = *reinterpret_cast<const float4*>(&xs[rbase + i][k4 * 4]);
            acc0[i] += xv.x * w0[0] + xv.y * w0[1] + xv.z * w0[2] + xv.w * w0[3];
            acc1[i] += xv.x * w1[0] + xv.y * w1[1] + xv.z * w1[2] + xv.w * w1[3];
        }
    }

    const float b0 = bias[f0];
    const float b1 = bias[f0 + 64];
#pragma unroll
    for (int i = 0; i < 16; ++i) {
        const int row = row0 + rbase + i;
        if (row < M) {
            h[(size_t)row * N_OUT + f0]      = acc0[i] + b0;
            h[(size_t)row * N_OUT + f0 + 64] = acc1[i] + b1;
        }
    }
}

// Scatter: out[dst] += w_e * h[src], 2 edges per 256-thread block (128 lanes/edge).
__global__ __launch_bounds__(256) void gcn_scatter(
    const int* __restrict__ ei, const float* __restrict__ ew,
    const float* __restrict__ h, float* __restrict__ out, int E, int M)
{
    const int e = blockIdx.x * 2 + (threadIdx.x >> 7);
    if (e >= E) return;
    const int f   = threadIdx.x & 127;
    const int dst = ei[e];          // row 0 of edge_index
    const int src = ei[(size_t)E + e];  // row 1 of edge_index
    if ((unsigned)dst >= (unsigned)M || (unsigned)src >= (unsigned)M) return;
    const float w = ew[e];
    const float v = w * h[(size_t)src * N_OUT + f];
    atomicAdd(&out[(size_t)dst * N_OUT + f], v);
}

extern "C" void kernel_launch(void* const* d_in, const int* in_sizes, int n_in,
                              void* d_out, int out_size, void* d_ws, size_t ws_size,
                              hipStream_t stream)
{
    const float* x    = (const float*)d_in[0];
    const int*   ei   = (const int*)d_in[1];
    const float* ew   = (const float*)d_in[2];
    const float* W    = (const float*)d_in[3];
    const float* bias = (const float*)d_in[4];
    float* out = (float*)d_out;

    const int M = in_sizes[0] / K_IN;   // 100000
    const int E = in_sizes[1] / 2;      // 3200000

    float* h = (float*)d_ws;            // M*128 fp32 = 51.2 MB scratch

    // harness poisons d_out once and never re-zeros between replays
    hipMemsetAsync(d_out, 0, (size_t)out_size * sizeof(float), stream);

    const int gblocks = (M + TILE_ROWS - 1) / TILE_ROWS;
    gcn_gemm<<<gblocks, 256, 0, stream>>>(x, W, bias, h, M);

    const int sblocks = (E + 1) / 2;
    gcn_scatter<<<sblocks, 256, 0, stream>>>(ei, ew, h, out, E, M);
}

// Round 2
// 740.694 us; speedup vs baseline: 2.1236x; 2.1236x over previous
//
#include <hip/hip_runtime.h>

#define K_IN  256
#define N_OUT 128
#define TILE_ROWS 64
#define SCAN_CHUNK 1024   // elements of cnt[] per scan block

// ---------------- GEMM: h[M][128] = x[M][256] @ W[256][128] + b ----------------
__global__ __launch_bounds__(256) void gcn_gemm(
    const float* __restrict__ x, const float* __restrict__ W,
    const float* __restrict__ bias, float* __restrict__ h, int M)
{
    __shared__ float xs[TILE_ROWS][K_IN];   // 64 KB
    const int tid  = threadIdx.x;
    const int row0 = blockIdx.x * TILE_ROWS;

    const int nvec = TILE_ROWS * (K_IN / 4);
    for (int i = tid; i < nvec; i += 256) {
        const int r = i >> 6;
        const int c = i & 63;
        float4 v = make_float4(0.f, 0.f, 0.f, 0.f);
        const int row = row0 + r;
        if (row < M) v = reinterpret_cast<const float4*>(x + (size_t)row * K_IN)[c];
        reinterpret_cast<float4*>(&xs[r][0])[c] = v;
    }
    __syncthreads();

    const int f0    = tid & 63;
    const int rbase = (tid >> 6) * 16;

    float acc0[16], acc1[16];
#pragma unroll
    for (int i = 0; i < 16; ++i) { acc0[i] = 0.f; acc1[i] = 0.f; }

#pragma unroll 2
    for (int k4 = 0; k4 < K_IN / 4; ++k4) {
        float w0[4], w1[4];
#pragma unroll
        for (int j = 0; j < 4; ++j) {
            w0[j] = W[(size_t)(k4 * 4 + j) * N_OUT + f0];
            w1[j] = W[(size_t)(k4 * 4 + j) * N_OUT + f0 + 64];
        }
#pragma unroll
        for (int i = 0; i < 16; ++i) {
            const float4 xv = *reinterpret_cast<const float4*>(&xs[rbase + i][k4 * 4]);
            acc0[i] += xv.x * w0[0] + xv.y * w0[1] + xv.z * w0[2] + xv.w * w0[3];
            acc1[i] += xv.x * w1[0] + xv.y * w1[1] + xv.z * w1[2] + xv.w * w1[3];
        }
    }

    const float b0 = bias[f0];
    const float b1 = bias[f0 + 64];
#pragma unroll
    for (int i = 0; i < 16; ++i) {
        const int row = row0 + rbase + i;
        if (row < M) {
            h[(size_t)row * N_OUT + f0]      = acc0[i] + b0;
            h[(size_t)row * N_OUT + f0 + 64] = acc1[i] + b1;
        }
    }
}

// ---------------- CSR build ----------------
__global__ __launch_bounds__(256) void hist_kernel(
    const int* __restrict__ dst, int E, int M, int* __restrict__ cnt)
{
    int i = blockIdx.x * blockDim.x + threadIdx.x;
    const int stride = gridDim.x * blockDim.x;
    for (; i < E; i += stride) {
        const int d = dst[i];
        if ((unsigned)d < (unsigned)M) atomicAdd(&cnt[d], 1);
    }
}

// S1: per-block sums of SCAN_CHUNK counts
__global__ __launch_bounds__(256) void scan_block_sums(
    const int* __restrict__ cnt, int M, int* __restrict__ bsum)
{
    __shared__ int sd[256];
    const int base = blockIdx.x * SCAN_CHUNK + threadIdx.x * 4;
    int s = 0;
#pragma unroll
    for (int j = 0; j < 4; ++j) { const int idx = base + j; if (idx < M) s += cnt[idx]; }
    sd[threadIdx.x] = s; __syncthreads();
    for (int off = 128; off > 0; off >>= 1) {
        if (threadIdx.x < off) sd[threadIdx.x] += sd[threadIdx.x + off];
        __syncthreads();
    }
    if (threadIdx.x == 0) bsum[blockIdx.x] = sd[0];
}

// S2: exclusive-scan the (<=1024) block sums in place; offsets[M] = total
__global__ __launch_bounds__(1024) void scan_sums(
    int* __restrict__ bsum, int nb, int* __restrict__ offsets, int M)
{
    __shared__ int sd[1024];
    const int t = threadIdx.x;
    const int v = (t < nb) ? bsum[t] : 0;
    sd[t] = v; __syncthreads();
    for (int off = 1; off < 1024; off <<= 1) {
        const int add = (t >= off) ? sd[t - off] : 0;
        __syncthreads();
        sd[t] += add;
        __syncthreads();
    }
    if (t < nb) bsum[t] = sd[t] - v;          // exclusive
    if (t == nb - 1) offsets[M] = sd[t];      // total == #valid edges
}

// S3: full exclusive scan -> offsets[0..M), plus cursor copy
__global__ __launch_bounds__(256) void scan_write_offsets(
    const int* __restrict__ cnt, int M, const int* __restrict__ bsum,
    int* __restrict__ offsets, int* __restrict__ cursor)
{
    __shared__ int sd[256];
    const int t = threadIdx.x;
    const int base = blockIdx.x * SCAN_CHUNK + t * 4;
    int v[4]; int s = 0;
#pragma unroll
    for (int j = 0; j < 4; ++j) { const int idx = base + j; v[j] = (idx < M) ? cnt[idx] : 0; s += v[j]; }
    sd[t] = s; __syncthreads();
    const int own = s;
    for (int off = 1; off < 256; off <<= 1) {
        const int add = (t >= off) ? sd[t - off] : 0;
        __syncthreads();
        sd[t] += add;
        __syncthreads();
    }
    int run = bsum[blockIdx.x] + (sd[t] - own);
#pragma unroll
    for (int j = 0; j < 4; ++j) {
        const int idx = base + j;
        if (idx < M) { offsets[idx] = run; cursor[idx] = run; run += v[j]; }
    }
}

__global__ __launch_bounds__(256) void fill_csr(
    const int* __restrict__ ei, const float* __restrict__ ew, int E, int M,
    int* __restrict__ cursor, int2* __restrict__ csr)
{
    int i = blockIdx.x * blockDim.x + threadIdx.x;
    const int stride = gridDim.x * blockDim.x;
    for (; i < E; i += stride) {
        const int d = ei[i];
        const int s = ei[(size_t)E + i];
        if ((unsigned)d >= (unsigned)M || (unsigned)s >= (unsigned)M) continue;
        const float w = ew[i];
        const int pos = atomicAdd(&cursor[d], 1);
        csr[pos] = make_int2(s, __float_as_int(w));
    }
}

// ---------------- Gather: one wave per node, float2 per lane ----------------
__global__ __launch_bounds__(256) void gather_kernel(
    const int* __restrict__ offsets, const int2* __restrict__ csr,
    const float* __restrict__ h, float* __restrict__ out, int M)
{
    const int n = blockIdx.x * 4 + (threadIdx.x >> 6);
    if (n >= M) return;
    const int lane = threadIdx.x & 63;
    const int s = offsets[n];
    const int e = offsets[n + 1];
    float2 acc = make_float2(0.f, 0.f);
    int i = s;
    for (; i + 1 < e; i += 2) {
        const int2 p0 = csr[i];
        const int2 p1 = csr[i + 1];
        const float w0 = __int_as_float(p0.y);
        const float w1 = __int_as_float(p1.y);
        const float2 h0 = *reinterpret_cast<const float2*>(h + (size_t)p0.x * N_OUT + lane * 2);
        const float2 h1 = *reinterpret_cast<const float2*>(h + (size_t)p1.x * N_OUT + lane * 2);
        acc.x += w0 * h0.x + w1 * h1.x;
        acc.y += w0 * h0.y + w1 * h1.y;
    }
    if (i < e) {
        const int2 p = csr[i];
        const float w = __int_as_float(p.y);
        const float2 hv = *reinterpret_cast<const float2*>(h + (size_t)p.x * N_OUT + lane * 2);
        acc.x += w * hv.x;
        acc.y += w * hv.y;
    }
    *reinterpret_cast<float2*>(out + (size_t)n * N_OUT + lane * 2) = acc;
}

// ---------------- fallback atomic scatter (if ws too small) ----------------
__global__ __launch_bounds__(256) void gcn_scatter(
    const int* __restrict__ ei, const float* __restrict__ ew,
    const float* __restrict__ h, float* __restrict__ out, int E, int M)
{
    const int e = blockIdx.x * 2 + (threadIdx.x >> 7);
    if (e >= E) return;
    const int f   = threadIdx.x & 127;
    const int dst = ei[e];
    const int src = ei[(size_t)E + e];
    if ((unsigned)dst >= (unsigned)M || (unsigned)src >= (unsigned)M) return;
    const float w = ew[e];
    atomicAdd(&out[(size_t)dst * N_OUT + f], w * h[(size_t)src * N_OUT + f]);
}

extern "C" void kernel_launch(void* const* d_in, const int* in_sizes, int n_in,
                              void* d_out, int out_size, void* d_ws, size_t ws_size,
                              hipStream_t stream)
{
    const float* x    = (const float*)d_in[0];
    const int*   ei   = (const int*)d_in[1];
    const float* ew   = (const float*)d_in[2];
    const float* W    = (const float*)d_in[3];
    const float* bias = (const float*)d_in[4];
    float* out = (float*)d_out;

    const int M = in_sizes[0] / K_IN;   // 100000
    const int E = in_sizes[1] / 2;      // 3200000

    // ---- workspace layout ----
    auto align256 = [](size_t v) { return (v + 255) & ~(size_t)255; };
    const size_t o_h      = 0;
    const size_t o_cnt    = align256(o_h + (size_t)M * N_OUT * sizeof(float));
    const size_t o_off    = align256(o_cnt + (size_t)M * sizeof(int));
    const size_t o_cur    = align256(o_off + (size_t)(M + 1) * sizeof(int));
    const size_t o_bsum   = align256(o_cur + (size_t)M * sizeof(int));
    const size_t o_csr    = align256(o_bsum + (size_t)1024 * sizeof(int));
    const size_t required = o_csr + (size_t)E * sizeof(int2);

    float* h = (float*)((char*)d_ws + o_h);
    const int nb = (M + SCAN_CHUNK - 1) / SCAN_CHUNK;

    const int gblocks = (M + TILE_ROWS - 1) / TILE_ROWS;
    gcn_gemm<<<gblocks, 256, 0, stream>>>(x, W, bias, h, M);

    if (ws_size < required || nb > 1024) {
        // fallback: proven atomic path
        hipMemsetAsync(d_out, 0, (size_t)out_size * sizeof(float), stream);
        const int sblocks = (E + 1) / 2;
        gcn_scatter<<<sblocks, 256, 0, stream>>>(ei, ew, h, out, E, M);
        return;
    }

    int*  cnt     = (int*)((char*)d_ws + o_cnt);
    int*  offsets = (int*)((char*)d_ws + o_off);
    int*  cursor  = (int*)((char*)d_ws + o_cur);
    int*  bsum    = (int*)((char*)d_ws + o_bsum);
    int2* csr     = (int2*)((char*)d_ws + o_csr);

    hipMemsetAsync(cnt, 0, (size_t)M * sizeof(int), stream);

    hist_kernel<<<2048, 256, 0, stream>>>(ei, E, M, cnt);
    scan_block_sums<<<nb, 256, 0, stream>>>(cnt, M, bsum);
    scan_sums<<<1, 1024, 0, stream>>>(bsum, nb, offsets, M);
    scan_write_offsets<<<nb, 256, 0, stream>>>(cnt, M, bsum, offsets, cursor);
    fill_csr<<<2048, 256, 0, stream>>>(ei, ew, E, M, cursor, csr);

    const int ablocks = (M + 3) / 4;
    gather_kernel<<<ablocks, 256, 0, stream>>>(offsets, csr, h, out, M);
}

// Round 3
// 662.639 us; speedup vs baseline: 2.3737x; 1.1178x over previous
//
#include <hip/hip_runtime.h>

#define K_IN   256
#define N_OUT  128
#define BM     32
#define SCAN_CHUNK 1024

typedef short bf16x8 __attribute__((ext_vector_type(8)));
typedef float f32x4  __attribute__((ext_vector_type(4)));

static __device__ __forceinline__ unsigned short f2bf(float f) {
    unsigned u = __float_as_uint(f);
    unsigned r = (u + 0x7FFF + ((u >> 16) & 1)) >> 16;   // RNE
    return (unsigned short)r;
}
static __device__ __forceinline__ float bf2f(unsigned short b) {
    return __uint_as_float(((unsigned)b) << 16);
}

// ---- prep: W[256][128] fp32 -> pre-swizzled bf16 LDS image WbT[n=128][k=256] (64KB)
// element W[k][n] at byte n*512 + (((2k)&~15) ^ ((n&7)<<4)) + ((2k)&15)
__global__ __launch_bounds__(256) void prep_w(const float* __restrict__ W, char* __restrict__ wbt)
{
    const int t = blockIdx.x * 256 + threadIdx.x;
    if (t >= N_OUT * 32) return;
    const int n = t >> 5;          // 0..127
    const int c = t & 31;          // chunk of 8 k's
    unsigned v[4];
#pragma unroll
    for (int p = 0; p < 4; ++p) {
        const unsigned lo = f2bf(W[(size_t)(c * 8 + 2 * p)     * N_OUT + n]);
        const unsigned hi = f2bf(W[(size_t)(c * 8 + 2 * p + 1) * N_OUT + n]);
        v[p] = lo | (hi << 16);
    }
    const int byte = n * 512 + ((c * 16) ^ ((n & 7) << 4));
    *reinterpret_cast<uint4*>(wbt + byte) = make_uint4(v[0], v[1], v[2], v[3]);
}

// ---- GEMM (bf16 MFMA) + fused dst-histogram
// block = 256 thr = 4 waves (2x2), tile 32 rows x 128 cols, K=256 fully LDS-resident.
// LDS: [0,64K) = W image, [64K,80K) = x tile (32 rows x 512B, XOR-swizzled)
__global__ __launch_bounds__(256) void gemm_hist(
    const float* __restrict__ x, const uint4* __restrict__ wbt,
    const float* __restrict__ bias, unsigned short* __restrict__ hb,
    const int* __restrict__ ei, int* __restrict__ cnt, int M, int E)
{
    __shared__ uint4 smem4[81920 / 16];
    char* smem = (char*)smem4;
    const int tid  = threadIdx.x;
    const int row0 = blockIdx.x * BM;

    // stage W image (linear 64KB copy; source is pre-swizzled)
    {
        uint4* wl = (uint4*)smem;
#pragma unroll
        for (int it = 0; it < 16; ++it) {
            const int idx = it * 256 + tid;
            wl[idx] = wbt[idx];
        }
    }
    // stage x tile: row = tid>>3, kseg = tid&7 (32 floats), convert fp32->bf16, swizzled write
    {
        const int r    = tid >> 3;
        const int ks   = tid & 7;
        const int grow = row0 + r;
        char* xbase    = smem + 65536 + r * 512;
        const int swz  = (r & 7) << 4;
        if (grow < M) {
            const float4* src = reinterpret_cast<const float4*>(x + (size_t)grow * K_IN + ks * 32);
#pragma unroll
            for (int q = 0; q < 8; ++q) {
                const float4 f = src[q];
                uint2 v;
                v.x = (unsigned)f2bf(f.x) | ((unsigned)f2bf(f.y) << 16);
                v.y = (unsigned)f2bf(f.z) | ((unsigned)f2bf(f.w) << 16);
                const int kb = ks * 64 + q * 8;
                *reinterpret_cast<uint2*>(xbase + (((kb & ~15) ^ swz) | (kb & 15))) = v;
            }
        } else {
            const uint2 z = make_uint2(0u, 0u);
#pragma unroll
            for (int q = 0; q < 8; ++q) {
                const int kb = ks * 64 + q * 8;
                *reinterpret_cast<uint2*>(xbase + (((kb & ~15) ^ swz) | (kb & 15))) = z;
            }
        }
    }
    __syncthreads();

    const int lane = tid & 63;
    const int wv   = tid >> 6;
    const int wr   = wv >> 1;          // 0..1: row half
    const int wc   = wv & 1;           // 0..1: col half
    const int l15  = lane & 15;
    const int lk   = lane >> 4;        // k-group 0..3

    const int  arow = wr * 16 + l15;
    const char* xrow = smem + 65536 + arow * 512;
    const int  aswz = (arow & 7) << 4;
    const int  bswz = (l15 & 7) << 4;
    const char* brow0 = smem + (size_t)(wc * 64 + l15) * 512;   // +j*16*512 per n-frag

    f32x4 acc[4] = {};

#pragma unroll
    for (int ks = 0; ks < 8; ++ks) {
        const int kb = ks * 64 + lk * 16;
        const bf16x8 a = *reinterpret_cast<const bf16x8*>(xrow + (kb ^ aswz));
        const int bk = kb ^ bswz;
#pragma unroll
        for (int j = 0; j < 4; ++j) {
            const bf16x8 b = *reinterpret_cast<const bf16x8*>(brow0 + j * (16 * 512) + bk);
            acc[j] = __builtin_amdgcn_mfma_f32_16x16x32_bf16(a, b, acc[j], 0, 0, 0);
        }
    }

    // epilogue: +bias, cvt bf16, store. C/D: col = lane&15, row = (lane>>4)*4 + reg
#pragma unroll
    for (int j = 0; j < 4; ++j) {
        const int gcol = wc * 64 + j * 16 + l15;
        const float bv = bias[gcol];
#pragma unroll
        for (int r = 0; r < 4; ++r) {
            const int grow = row0 + wr * 16 + lk * 4 + r;
            if (grow < M)
                hb[(size_t)grow * N_OUT + gcol] = f2bf(acc[j][r] + bv);
        }
    }

    // fused histogram of dst (independent of GEMM results, overlaps across blocks)
    const int stride = gridDim.x * 256;
    for (int i = blockIdx.x * 256 + tid; i < E; i += stride) {
        const int d = ei[i];
        const int s = ei[(size_t)E + i];
        if ((unsigned)d < (unsigned)M && (unsigned)s < (unsigned)M) atomicAdd(&cnt[d], 1);
    }
}

// ---- scans (as round 2) ----
__global__ __launch_bounds__(256) void scan_block_sums(
    const int* __restrict__ cnt, int M, int* __restrict__ bsum)
{
    __shared__ int sd[256];
    const int base = blockIdx.x * SCAN_CHUNK + threadIdx.x * 4;
    int s = 0;
#pragma unroll
    for (int j = 0; j < 4; ++j) { const int idx = base + j; if (idx < M) s += cnt[idx]; }
    sd[threadIdx.x] = s; __syncthreads();
    for (int off = 128; off > 0; off >>= 1) {
        if (threadIdx.x < off) sd[threadIdx.x] += sd[threadIdx.x + off];
        __syncthreads();
    }
    if (threadIdx.x == 0) bsum[blockIdx.x] = sd[0];
}

__global__ __launch_bounds__(1024) void scan_sums(
    int* __restrict__ bsum, int nb, int* __restrict__ offsets, int M)
{
    __shared__ int sd[1024];
    const int t = threadIdx.x;
    const int v = (t < nb) ? bsum[t] : 0;
    sd[t] = v; __syncthreads();
    for (int off = 1; off < 1024; off <<= 1) {
        const int add = (t >= off) ? sd[t - off] : 0;
        __syncthreads();
        sd[t] += add;
        __syncthreads();
    }
    if (t < nb) bsum[t] = sd[t] - v;
    if (t == nb - 1) offsets[M] = sd[t];
}

__global__ __launch_bounds__(256) void scan_write_offsets(
    const int* __restrict__ cnt, int M, const int* __restrict__ bsum,
    int* __restrict__ offsets, int* __restrict__ cursor)
{
    __shared__ int sd[256];
    const int t = threadIdx.x;
    const int base = blockIdx.x * SCAN_CHUNK + t * 4;
    int v[4]; int s = 0;
#pragma unroll
    for (int j = 0; j < 4; ++j) { const int idx = base + j; v[j] = (idx < M) ? cnt[idx] : 0; s += v[j]; }
    sd[t] = s; __syncthreads();
    const int own = s;
    for (int off = 1; off < 256; off <<= 1) {
        const int add = (t >= off) ? sd[t - off] : 0;
        __syncthreads();
        sd[t] += add;
        __syncthreads();
    }
    int run = bsum[blockIdx.x] + (sd[t] - own);
#pragma unroll
    for (int j = 0; j < 4; ++j) {
        const int idx = base + j;
        if (idx < M) { offsets[idx] = run; cursor[idx] = run; run += v[j]; }
    }
}

// ---- fill: csr holds edge id only (4B -> halves dirty-line amplification)
__global__ __launch_bounds__(256) void fill_eid(
    const int* __restrict__ ei, int E, int M,
    int* __restrict__ cursor, int* __restrict__ csr)
{
    int i = blockIdx.x * blockDim.x + threadIdx.x;
    const int stride = gridDim.x * blockDim.x;
    for (; i < E; i += stride) {
        const int d = ei[i];
        const int s = ei[(size_t)E + i];
        if ((unsigned)d >= (unsigned)M || (unsigned)s >= (unsigned)M) continue;
        csr[atomicAdd(&cursor[d], 1)] = i;
    }
}

// ---- gather: 1 wave/node; lane owns feat pair (2*lane, 2*lane+1); h is bf16
__global__ __launch_bounds__(256) void gather_kernel(
    const int* __restrict__ offsets, const int* __restrict__ csr,
    const int* __restrict__ ei, const float* __restrict__ ew,
    const unsigned short* __restrict__ hb, float* __restrict__ out, int M, int E)
{
    const int n = blockIdx.x * 4 + (threadIdx.x >> 6);
    if (n >= M) return;
    const int lane = threadIdx.x & 63;
    const int beg = offsets[n], end = offsets[n + 1];
    const int* __restrict__ srcs = ei + E;
    float ax = 0.f, ay = 0.f;
    int i = beg;
    for (; i + 4 <= end; i += 4) {
        const int e0 = csr[i], e1 = csr[i + 1], e2 = csr[i + 2], e3 = csr[i + 3];
        const int s0 = srcs[e0], s1 = srcs[e1], s2 = srcs[e2], s3 = srcs[e3];
        const float w0 = ew[e0], w1 = ew[e1], w2 = ew[e2], w3 = ew[e3];
        const unsigned u0 = reinterpret_cast<const unsigned*>(hb + (size_t)s0 * N_OUT)[lane];
        const unsigned u1 = reinterpret_cast<const unsigned*>(hb + (size_t)s1 * N_OUT)[lane];
        const unsigned u2 = reinterpret_cast<const unsigned*>(hb + (size_t)s2 * N_OUT)[lane];
        const unsigned u3 = reinterpret_cast<const unsigned*>(hb + (size_t)s3 * N_OUT)[lane];
        ax += w0 * bf2f((unsigned short)u0) + w1 * bf2f((unsigned short)u1)
            + w2 * bf2f((unsigned short)u2) + w3 * bf2f((unsigned short)u3);
        ay += w0 * bf2f((unsigned short)(u0 >> 16)) + w1 * bf2f((unsigned short)(u1 >> 16))
            + w2 * bf2f((unsigned short)(u2 >> 16)) + w3 * bf2f((unsigned short)(u3 >> 16));
    }
    for (; i < end; ++i) {
        const int e0 = csr[i];
        const int s0 = srcs[e0];
        const float w0 = ew[e0];
        const unsigned u0 = reinterpret_cast<const unsigned*>(hb + (size_t)s0 * N_OUT)[lane];
        ax += w0 * bf2f((unsigned short)u0);
        ay += w0 * bf2f((unsigned short)(u0 >> 16));
    }
    reinterpret_cast<float2*>(out + (size_t)n * N_OUT)[lane] = make_float2(ax, ay);
}

extern "C" void kernel_launch(void* const* d_in, const int* in_sizes, int n_in,
                              void* d_out, int out_size, void* d_ws, size_t ws_size,
                              hipStream_t stream)
{
    const float* x    = (const float*)d_in[0];
    const int*   ei   = (const int*)d_in[1];
    const float* ew   = (const float*)d_in[2];
    const float* W    = (const float*)d_in[3];
    const float* bias = (const float*)d_in[4];
    float* out = (float*)d_out;

    const int M = in_sizes[0] / K_IN;   // 100000
    const int E = in_sizes[1] / 2;      // 3200000

    // workspace layout (~40MB; harness provides >=77MB, proven round 2)
    auto align256 = [](size_t v) { return (v + 255) & ~(size_t)255; };
    const size_t o_hb   = 0;
    const size_t o_cnt  = align256(o_hb + (size_t)M * N_OUT * sizeof(unsigned short));
    const size_t o_off  = align256(o_cnt + (size_t)M * sizeof(int));
    const size_t o_cur  = align256(o_off + (size_t)(M + 1) * sizeof(int));
    const size_t o_bsum = align256(o_cur + (size_t)M * sizeof(int));
    const size_t o_wbt  = align256(o_bsum + (size_t)1024 * sizeof(int));
    const size_t o_csr  = align256(o_wbt + (size_t)65536);

    unsigned short* hb      = (unsigned short*)((char*)d_ws + o_hb);
    int*            cnt     = (int*)((char*)d_ws + o_cnt);
    int*            offsets = (int*)((char*)d_ws + o_off);
    int*            cursor  = (int*)((char*)d_ws + o_cur);
    int*            bsum    = (int*)((char*)d_ws + o_bsum);
    char*           wbt     = (char*)d_ws + o_wbt;
    int*            csr     = (int*)((char*)d_ws + o_csr);

    const int nb = (M + SCAN_CHUNK - 1) / SCAN_CHUNK;   // 98

    hipMemsetAsync(cnt, 0, (size_t)M * sizeof(int), stream);
    prep_w<<<16, 256, 0, stream>>>(W, wbt);
    gemm_hist<<<(M + BM - 1) / BM, 256, 0, stream>>>(
        x, (const uint4*)wbt, bias, hb, ei, cnt, M, E);
    scan_block_sums<<<nb, 256, 0, stream>>>(cnt, M, bsum);
    scan_sums<<<1, 1024, 0, stream>>>(bsum, nb, offsets, M);
    scan_write_offsets<<<nb, 256, 0, stream>>>(cnt, M, bsum, offsets, cursor);
    fill_eid<<<2048, 256, 0, stream>>>(ei, E, M, cursor, csr);
    gather_kernel<<<(M + 3) / 4, 256, 0, stream>>>(offsets, csr, ei, ew, hb, out, M, E);
}